// Round 1
// baseline (791.083 us; speedup 1.0000x reference)
//
#include <hip/hip_runtime.h>
#include <hip/hip_bf16.h>

#define B_TRIPLES 1024
#define N_ENT 100000
#define RANK 256
#define MAX_NB 50

typedef float f32x4 __attribute__((ext_vector_type(4)));
typedef __bf16 bf16x8 __attribute__((ext_vector_type(8)));

__device__ __forceinline__ unsigned short f32_to_bf16_bits(float f) {
    unsigned u = __float_as_uint(f);
    unsigned r = ((u >> 16) & 1u) + 0x7fffu;
    return (unsigned short)((u + r) >> 16);
}

// ---------------------------------------------------------------------------
// Kernel 1: one block per triple. Computes lhs/rel/rhs gathers, w, attention
// over 50 neighbors, e_c, gate g, and q = lhs*rel*gated_e_c (bf16, to ws).
// ---------------------------------------------------------------------------
__global__ __launch_bounds__(256) void triple_kernel(
    const int* __restrict__ x, const int* __restrict__ nb_idx,
    const float* __restrict__ lhs_w, const float* __restrict__ rel_w,
    const float* __restrict__ rhs_w,
    const float* __restrict__ W_w, const float* __restrict__ W_b,
    const float* __restrict__ W2_w, const float* __restrict__ W2_b,
    const float* __restrict__ Wo_w, const float* __restrict__ Wo_b,
    const float* __restrict__ Uo_w, const float* __restrict__ Uo_b,
    float* __restrict__ out_tail, unsigned short* __restrict__ qb)
{
    __shared__ float trp[2 * RANK];          // [lhs | rel], reused as ec_pre
    __shared__ float nb_s[MAX_NB * RANK];    // staged neighbor embeddings
    __shared__ float w_s[RANK];
    __shared__ float alpha_s[MAX_NB];
    __shared__ int   nbrow[MAX_NB];
    __shared__ float red[8];

    const int b    = blockIdx.x;
    const int k    = threadIdx.x;     // 0..255
    const int lane = k & 63;
    const int wv   = k >> 6;

    const int i0 = x[b * 3 + 0];
    const int i1 = x[b * 3 + 1];
    const int i2 = x[b * 3 + 2];

    const float lhs  = lhs_w[(size_t)i0 * RANK + k];
    const float rel  = rel_w[(size_t)i1 * RANK + k];
    const float rhsv = rhs_w[(size_t)i2 * RANK + k];

    // small outputs: lhs, rel, rhs (e_c written later)
    out_tail[0 * B_TRIPLES * RANK + b * RANK + k] = lhs;
    out_tail[1 * B_TRIPLES * RANK + b * RANK + k] = rel;
    out_tail[2 * B_TRIPLES * RANK + b * RANK + k] = rhsv;

    trp[k]        = lhs;
    trp[RANK + k] = rel;
    if (k < MAX_NB) nbrow[k] = nb_idx[b * MAX_NB + k];
    __syncthreads();

    // stage neighbor embeddings (coalesced along k)
    for (int m = 0; m < MAX_NB; ++m)
        nb_s[m * RANK + k] = rhs_w[(size_t)nbrow[m] * RANK + k];

    // w[k] = W_b[k] + sum_j W_w[k,j] * trp[j]   (row reads are L2-cached)
    float acc = W_b[k];
    const float4* Wr = (const float4*)(W_w + (size_t)k * (2 * RANK));
    #pragma unroll 8
    for (int j = 0; j < (2 * RANK) / 4; ++j) {
        float4 w4 = Wr[j];
        acc += w4.x * trp[4 * j + 0] + w4.y * trp[4 * j + 1]
             + w4.z * trp[4 * j + 2] + w4.w * trp[4 * j + 3];
    }
    w_s[k] = acc;
    __syncthreads();   // w_s + nb_s ready

    // scores[m] = <w, nb_E[m]>, one wave per m (round-robin)
    for (int m = wv; m < MAX_NB; m += 4) {
        float p = 0.f;
        #pragma unroll
        for (int t = 0; t < 4; ++t) {
            int kk = lane + 64 * t;
            p += w_s[kk] * nb_s[m * RANK + kk];
        }
        #pragma unroll
        for (int off = 32; off > 0; off >>= 1) p += __shfl_down(p, off);
        if (lane == 0) alpha_s[m] = p;
    }
    __syncthreads();

    // softmax over 50 (wave 0)
    if (wv == 0) {
        float v = (lane < MAX_NB) ? alpha_s[lane] : -1e30f;
        float mx = v;
        #pragma unroll
        for (int off = 1; off < 64; off <<= 1) mx = fmaxf(mx, __shfl_xor(mx, off));
        float e = (lane < MAX_NB) ? __expf(v - mx) : 0.f;
        float s = e;
        #pragma unroll
        for (int off = 1; off < 64; off <<= 1) s += __shfl_xor(s, off);
        if (lane < MAX_NB) alpha_s[lane] = e / s;
    }
    __syncthreads();

    // ec_pre[k] = sum_m alpha[m] * nb_E[m,k]
    float ecp = 0.f;
    for (int m = 0; m < MAX_NB; ++m) ecp += alpha_s[m] * nb_s[m * RANK + k];
    __syncthreads();
    trp[k] = ecp;                    // reuse trp[0..255] as ec_pre
    __syncthreads();

    // e_c[k] = W2_b[k] + sum_j W2_w[k,j] * ec_pre[j]
    float ec = W2_b[k];
    const float4* W2r = (const float4*)(W2_w + (size_t)k * RANK);
    #pragma unroll 8
    for (int j = 0; j < RANK / 4; ++j) {
        float4 w4 = W2r[j];
        ec += w4.x * trp[4 * j + 0] + w4.y * trp[4 * j + 1]
            + w4.z * trp[4 * j + 2] + w4.w * trp[4 * j + 3];
    }
    out_tail[3 * B_TRIPLES * RANK + b * RANK + k] = ec;

    // g = sigmoid(<lhs*rel, Uo> + Uo_b + <e_c, Wo> + Wo_b)
    float part = lhs * rel * Uo_w[k] + ec * Wo_w[k];
    #pragma unroll
    for (int off = 32; off > 0; off >>= 1) part += __shfl_down(part, off);
    if (lane == 0) red[wv] = part;
    __syncthreads();
    if (k == 0) {
        float s = red[0] + red[1] + red[2] + red[3] + Uo_b[0] + Wo_b[0];
        red[4] = 1.f / (1.f + __expf(-s));
    }
    __syncthreads();
    const float g = red[4];
    const float gated = g * ec + (1.f - g);
    qb[b * RANK + k] = f32_to_bf16_bits(lhs * rel * gated);
}

// ---------------------------------------------------------------------------
// Kernel 2: rhs_w f32 -> bf16 (25.6M elems, 8 per thread)
// ---------------------------------------------------------------------------
__global__ __launch_bounds__(256) void cvt_kernel(
    const float* __restrict__ in, unsigned short* __restrict__ outp)
{
    size_t t = (size_t)blockIdx.x * 256 + threadIdx.x;
    const float4* p = (const float4*)in + 2 * t;
    float4 a = p[0], c = p[1];
    uint4 o;
    o.x = (unsigned)f32_to_bf16_bits(a.x) | ((unsigned)f32_to_bf16_bits(a.y) << 16);
    o.y = (unsigned)f32_to_bf16_bits(a.z) | ((unsigned)f32_to_bf16_bits(a.w) << 16);
    o.z = (unsigned)f32_to_bf16_bits(c.x) | ((unsigned)f32_to_bf16_bits(c.y) << 16);
    o.w = (unsigned)f32_to_bf16_bits(c.z) | ((unsigned)f32_to_bf16_bits(c.w) << 16);
    ((uint4*)outp)[t] = o;
}

// ---------------------------------------------------------------------------
// Kernel 3: tot_forward[b,e] = sum_k q[b,k] * rhs[e,k]  via bf16 MFMA 16x16x32.
// Block = 8 waves (512 thr). Wave wv: rows b in [blockIdx.y*512 + wv*64, +64),
// cols e in [blockIdx.x*64, +64). K=256 fully unrolled. Both operands are
// row-major in k -> direct 16B fragment loads, no LDS.
// A-frag: lane holds A[m=lane&15][k=quad*8+j]; B-frag: B[k=quad*8+j][n=lane&15].
// C/D: col = lane&15, row = quad*4 + reg   [m89/m91 verified mapping]
// ---------------------------------------------------------------------------
__global__ __launch_bounds__(512) void gemm_kernel(
    const unsigned short* __restrict__ rhsb,
    const unsigned short* __restrict__ qb,
    float* __restrict__ out)
{
    const int lane = threadIdx.x & 63;
    const int wv   = threadIdx.x >> 6;
    const int r    = lane & 15;
    const int quad = lane >> 4;

    const int e_blk  = blockIdx.x * 64;
    const int b_base = blockIdx.y * 512 + wv * 64;

    f32x4 acc[4][4] = {};

    #pragma unroll
    for (int kt = 0; kt < 8; ++kt) {
        const int ko = kt * 32 + quad * 8;
        union { uint4 u; bf16x8 v; } a[4], bb[4];
        #pragma unroll
        for (int tm = 0; tm < 4; ++tm) {
            const int brow = b_base + tm * 16 + r;
            a[tm].u = *(const uint4*)(qb + (size_t)brow * RANK + ko);
        }
        #pragma unroll
        for (int tn = 0; tn < 4; ++tn) {
            int e = e_blk + tn * 16 + r;
            if (e >= N_ENT) e = N_ENT - 1;      // clamp; store is guarded
            bb[tn].u = *(const uint4*)(rhsb + (size_t)e * RANK + ko);
        }
        #pragma unroll
        for (int tm = 0; tm < 4; ++tm)
            #pragma unroll
            for (int tn = 0; tn < 4; ++tn)
                acc[tm][tn] = __builtin_amdgcn_mfma_f32_16x16x32_bf16(
                    a[tm].v, bb[tn].v, acc[tm][tn], 0, 0, 0);
    }

    #pragma unroll
    for (int tm = 0; tm < 4; ++tm) {
        #pragma unroll
        for (int i = 0; i < 4; ++i) {
            const int brow = b_base + tm * 16 + quad * 4 + i;
            float* orow = out + (size_t)brow * N_ENT;
            #pragma unroll
            for (int tn = 0; tn < 4; ++tn) {
                const int e = e_blk + tn * 16 + r;
                if (e < N_ENT) orow[e] = acc[tm][tn][i];
            }
        }
    }
}

// ---------------------------------------------------------------------------
extern "C" void kernel_launch(void* const* d_in, const int* in_sizes, int n_in,
                              void* d_out, int out_size, void* d_ws, size_t ws_size,
                              hipStream_t stream)
{
    const int*   x     = (const int*)d_in[0];
    const int*   nb    = (const int*)d_in[1];
    const float* lhs_w = (const float*)d_in[2];
    const float* rel_w = (const float*)d_in[3];
    const float* rhs_w = (const float*)d_in[4];
    const float* W_w   = (const float*)d_in[5];
    const float* W_b   = (const float*)d_in[6];
    const float* W2_w  = (const float*)d_in[7];
    const float* W2_b  = (const float*)d_in[8];
    const float* Wo_w  = (const float*)d_in[9];
    const float* Wo_b  = (const float*)d_in[10];
    const float* Uo_w  = (const float*)d_in[11];
    const float* Uo_b  = (const float*)d_in[12];

    float* out      = (float*)d_out;
    float* out_tail = out + (size_t)B_TRIPLES * N_ENT;

    unsigned short* rhsb = (unsigned short*)d_ws;                 // 51.2 MB
    unsigned short* qb   = rhsb + (size_t)N_ENT * RANK;           // +512 KB

    triple_kernel<<<B_TRIPLES, 256, 0, stream>>>(
        x, nb, lhs_w, rel_w, rhs_w, W_w, W_b, W2_w, W2_b,
        Wo_w, Wo_b, Uo_w, Uo_b, out_tail, qb);

    // 100000*256 / 8 elems per thread / 256 threads = 12500 blocks
    cvt_kernel<<<12500, 256, 0, stream>>>(rhs_w, rhsb);

    // e blocks: ceil(100000/64) = 1563 ; b blocks: 1024/512 = 2
    gemm_kernel<<<dim3(1563, 2), 512, 0, stream>>>(rhsb, qb, out);

    (void)in_sizes; (void)n_in; (void)out_size; (void)ws_size;
}